// Round 12
// baseline (89.840 us; speedup 1.0000x reference)
//
#include <hip/hip_runtime.h>

#define FD 128
// deg pass: u8 LDS cells, 64 KB -> 65536 nodes/chunk
#define CHD 65536
#define NSLD 64
// S pass: u32 cells, 64 KB
#define CHS 16384
#define LOG2CHS 14
#define NSLS 16
#define QPB 512               // qwpack_part blocks
#define RXB 512               // reduce_x blocks
#define QSCALE 16777216.0f    // 2^24 (fallback path)
#define QINV   5.9604644775390625e-8f
#define QS14   16384.0f       // 2^14 (packed path)
#define QI14   6.103515625e-5f
#define SRCMASK 0x1FFFFu      // low 17 bits = src id

__device__ __forceinline__ unsigned quant_w(int dp1) {
    return (unsigned)(rsqrtf((float)dp1) * QSCALE + 0.5f);
}
__device__ __forceinline__ unsigned quant_w14(int dp1) {
    return (unsigned)(rsqrtf((float)dp1) * QS14 + 0.5f);   // <= 16384 (15 bits)
}

// Wave-level dtype probe (proven R6+): int64 => odd u32 words all zero.
__device__ __forceinline__ bool detect_is32_wave(const unsigned int* w, long long nwords) {
    const int lane = threadIdx.x & 63;
    const long long i0 = 2 * lane + 1, i1 = 2 * (lane + 64) + 1;
    unsigned acc = 0;
    if (i0 < nwords) acc |= w[i0];
    if (i1 < nwords) acc |= w[i1];
    return __ballot(acc != 0u) != 0ull;
}

__device__ __forceinline__ int4 ld_e4(const void* ei, bool is32, long long off, long long i) {
    if (is32) return *reinterpret_cast<const int4*>((const int*)ei + off + i);
    const long long* p = (const long long*)ei + off + i;
    longlong2 a = *reinterpret_cast<const longlong2*>(p);
    longlong2 b = *reinterpret_cast<const longlong2*>(p + 2);
    return make_int4((int)a.x, (int)a.y, (int)b.x, (int)b.y);
}
__device__ __forceinline__ int ld_e1(const void* ei, bool is32, long long idx) {
    return is32 ? ((const int*)ei)[idx] : (int)((const long long*)ei)[idx];
}

// ---- 1: deg histogram over dst, u8 LDS cells; also zeroes partition counters ----
__global__ __launch_bounds__(512) void hist_deg_kernel(
        const void* __restrict__ ei, unsigned int* __restrict__ psD,
        unsigned int* __restrict__ counts, long long E, long long SL, int nch) {
    __shared__ unsigned int hist[CHD / 4];   // 16384 words, 4 u8 cells each
    const int tid = threadIdx.x;
    if (blockIdx.x == 0 && tid < 16) counts[tid] = 0u;   // consumed 2 kernels later
    const bool is32 = detect_is32_wave((const unsigned int*)ei, 2 * E);
    const int b = blockIdx.x, c = b % nch, j = b / nch;
    const int lo = c * CHD;
    for (int i = tid; i < CHD / 4; i += 512) hist[i] = 0u;
    __syncthreads();
    const long long e0 = (long long)j * SL;
    long long e1 = e0 + SL; if (e1 > E) e1 = E; if (e1 < e0) e1 = e0;
    const long long e1v = e0 + ((e1 - e0) & ~3LL);
    for (long long i = e0 + (long long)tid * 4; i < e1v; i += 2048) {
        int4 d = ld_e4(ei, is32, E, i);
        unsigned u0 = (unsigned)(d.x - lo), u1 = (unsigned)(d.y - lo);
        unsigned u2 = (unsigned)(d.z - lo), u3 = (unsigned)(d.w - lo);
        if (u0 < CHD) atomicAdd(&hist[u0 >> 2], 1u << ((u0 & 3) * 8));
        if (u1 < CHD) atomicAdd(&hist[u1 >> 2], 1u << ((u1 & 3) * 8));
        if (u2 < CHD) atomicAdd(&hist[u2 >> 2], 1u << ((u2 & 3) * 8));
        if (u3 < CHD) atomicAdd(&hist[u3 >> 2], 1u << ((u3 & 3) * 8));
    }
    { long long it = e1v + tid;
      if (it < e1) { unsigned u = (unsigned)(ld_e1(ei, is32, E + it) - lo);
                     if (u < CHD) atomicAdd(&hist[u >> 2], 1u << ((u & 3) * 8)); } }
    __syncthreads();
    unsigned int* o = psD + (size_t)b * (CHD / 4);
    for (int w = tid; w < CHD / 4; w += 512) o[w] = hist[w];
}

// ---- 2: reduce u8 deg partials (4 nodes per word) ----
__global__ void deg_reduce_kernel(const unsigned int* __restrict__ psD,
                                  int* __restrict__ deg, long long n, int nch) {
    const long long tw = blockIdx.x * (long long)blockDim.x + threadIdx.x;
    if (tw >= (long long)nch * (CHD / 4)) return;
    const int cc = (int)(tw / (CHD / 4));
    const int w  = (int)(tw % (CHD / 4));
    unsigned s0 = 0, s1 = 0, s2 = 0, s3 = 0;
    for (int j = 0; j < NSLD; ++j) {
        unsigned v = psD[((size_t)j * nch + cc) * (CHD / 4) + w];
        s0 += v & 0xFFu; s1 += (v >> 8) & 0xFFu;
        s2 += (v >> 16) & 0xFFu; s3 += v >> 24;
    }
    const long long v0 = (long long)cc * CHD + 4 * w;
    if (v0 < n)     deg[v0]     = (int)s0;
    if (v0 + 1 < n) deg[v0 + 1] = (int)s1;
    if (v0 + 2 < n) deg[v0 + 2] = (int)s2;
    if (v0 + 3 < n) deg[v0 + 3] = (int)s3;
}

// ---- 3: pack (qw<<17|src) AND partition by src-chunk (single edge pass) ----
__global__ __launch_bounds__(512) void qwpack_part_kernel(
        const void* __restrict__ ei, const int* __restrict__ deg,
        unsigned int* __restrict__ counts, unsigned int* __restrict__ qpart,
        long long capC, long long E, int nch) {
    __shared__ unsigned int buf[8][1024];
    __shared__ int cnt[8], take[8], base[8];
    const int tid = threadIdx.x;
    const bool is32 = detect_is32_wave((const unsigned int*)ei, 2 * E);
    if (tid < 8) cnt[tid] = 0;
    __syncthreads();
    const long long e0 = (long long)blockIdx.x * E / QPB;
    const long long e1 = (long long)(blockIdx.x + 1) * E / QPB;
    for (long long s = e0; s < e1; s += 512) {
        const long long idx = s + tid;
        if (idx < e1) {
            const int src = ld_e1(ei, is32, idx);
            const int dst = ld_e1(ei, is32, E + idx);
            const unsigned p = (quant_w14(deg[dst] + 1) << 17) | (unsigned)src;
            const int c = src >> LOG2CHS;
            const int pos = atomicAdd(&cnt[c], 1);   // < 1024 guaranteed
            buf[c][pos] = p;
        }
        __syncthreads();
        if (tid < 8) {
            const int k = cnt[tid] & ~511;
            take[tid] = k;
            if (k) base[tid] = (int)atomicAdd(&counts[tid], (unsigned)k);
        }
        __syncthreads();
        for (int c = 0; c < nch; ++c) {
            const int k = take[c];
            if (k) {
                unsigned int* dp = qpart + (size_t)c * capC + base[c];
                for (int t = tid; t < k; t += 512) dp[t] = buf[c][t];
            }
        }
        __syncthreads();
        for (int c = 0; c < nch; ++c) {
            const int k = take[c], r = cnt[c] - k;
            if (k && r > 0)
                for (int t = tid; t < r; t += 512) buf[c][t] = buf[c][k + t];
        }
        __syncthreads();
        if (tid < 8) cnt[tid] -= take[tid];
        __syncthreads();
    }
    if (tid < 8) { take[tid] = cnt[tid];
                   if (cnt[tid]) base[tid] = (int)atomicAdd(&counts[tid], (unsigned)cnt[tid]); }
    __syncthreads();
    for (int c = 0; c < nch; ++c) {
        const int k = take[c];
        if (k) {
            unsigned int* dp = qpart + (size_t)c * capC + base[c];
            for (int t = tid; t < k; t += 512) dp[t] = buf[c][t];
        }
    }
}

// ---- 4: weighted src histogram over pre-partitioned stream (single pass) ----
__global__ __launch_bounds__(512) void hist_s_kernel(
        const unsigned int* __restrict__ qpart, const unsigned int* __restrict__ counts,
        unsigned int* __restrict__ psS, long long capC, int nch) {
    __shared__ unsigned int hist[CHS];
    const int tid = threadIdx.x;
    const int b = blockIdx.x, c = b % nch, j = b / nch;
    const int lo = c * CHS;
    for (int i = tid; i < CHS; i += 512) hist[i] = 0u;
    __syncthreads();
    const long long cc = counts[c];
    const long long i0 = cc * j / NSLS, i1 = cc * (j + 1) / NSLS;
    const unsigned int* src = qpart + (size_t)c * capC;
    for (long long i = i0 + tid; i < i1; i += 512) {
        const unsigned p = src[i];
        atomicAdd(&hist[(p & SRCMASK) - lo], p >> 17);   // always in-chunk
    }
    __syncthreads();
    unsigned int* o = psS + (size_t)b * CHS;
    for (int w = tid; w < CHS; w += 512) o[w] = hist[w];
}

// ---- 5: merged coef + x reduction (block-contiguous node ranges, R10-proven) ----
__global__ __launch_bounds__(256) void reduce_x_coef_kernel(
        const float* __restrict__ x, const int* __restrict__ deg,
        const unsigned int* __restrict__ psS, float* __restrict__ P,
        long long n, int nch) {
    __shared__ float lcoef[1024];
    __shared__ float4 sm4[256];
    const int tid = threadIdx.x;
    const long long vlo = (long long)blockIdx.x * n / RXB;
    const long long vhi = ((long long)blockIdx.x + 1) * n / RXB;
    const int nv = (int)(vhi - vlo);
    for (int t = tid; t < nv; t += 256) {
        const long long v = vlo + t;
        const int cc = (int)(v >> LOG2CHS);
        const int u  = (int)(v & (CHS - 1));
        unsigned s = 0;
        #pragma unroll
        for (int jj = 0; jj < NSLS; ++jj)
            s += psS[((size_t)jj * nch + cc) * CHS + u];
        const float dg = (float)(deg[v] + 1);
        const float di = rsqrtf(dg);
        lcoef[t] = di * ((float)s * QI14) + 1.0f / dg;
    }
    __syncthreads();
    float4 a = make_float4(0.f, 0.f, 0.f, 0.f);
    const long long i0 = vlo * (FD / 4), i1 = vhi * (FD / 4);
    for (long long i = i0 + tid; i < i1; i += 256) {
        const float cf = lcoef[(int)((i >> 5) - vlo)];
        const float4 xv = reinterpret_cast<const float4*>(x)[i];
        a.x += cf * xv.x; a.y += cf * xv.y; a.z += cf * xv.z; a.w += cf * xv.w;
    }
    const int lane = tid & 31, grp = tid >> 5;
    sm4[grp * 32 + lane] = a;
    __syncthreads();
    for (int s2 = 4; s2 > 0; s2 >>= 1) {
        if (grp < s2) {
            float4 o = sm4[(grp + s2) * 32 + lane];
            float4 m = sm4[grp * 32 + lane];
            m.x += o.x; m.y += o.y; m.z += o.z; m.w += o.w;
            sm4[grp * 32 + lane] = m;
        }
        __syncthreads();
    }
    if (tid < 32) reinterpret_cast<float4*>(P)[blockIdx.x * 32 + tid] = sm4[tid];
}

// ---- 6: fused colsum + W-matvec ----
__global__ __launch_bounds__(256) void colsum_final_kernel(
        const float* __restrict__ P, const float* __restrict__ Wm,
        const float* __restrict__ bias, float* __restrict__ out, float nn) {
    __shared__ float wrow[FD];
    __shared__ float red[256];
    const int f = blockIdx.x, tid = threadIdx.x;
    if (tid < FD) wrow[tid] = Wm[f * FD + tid];
    __syncthreads();
    float part = 0.f;
    for (int j = tid; j < RXB; j += 256) {
        const float4* Pj = reinterpret_cast<const float4*>(P + (size_t)j * FD);
        #pragma unroll
        for (int k = 0; k < FD / 4; ++k) {
            float4 p = Pj[k];
            part += wrow[4 * k] * p.x + wrow[4 * k + 1] * p.y +
                    wrow[4 * k + 2] * p.z + wrow[4 * k + 3] * p.w;
        }
    }
    red[tid] = part;
    __syncthreads();
    for (int s2 = 128; s2 > 0; s2 >>= 1) {
        if (tid < s2) red[tid] += red[tid + s2];
        __syncthreads();
    }
    if (tid == 0) out[f] = red[0] + nn * bias[f];
}

// ================= fallback (R2-proven global-atomic path) =================
__global__ void deg_fb(const void* __restrict__ ei, int* __restrict__ deg, long long E) {
    const bool is32 = detect_is32_wave((const unsigned int*)ei, 2 * E);
    const long long st = (long long)gridDim.x * blockDim.x;
    long long i = blockIdx.x * (long long)blockDim.x + threadIdx.x;
    for (; i < E; i += st) atomicAdd(&deg[ld_e1(ei, is32, E + i)], 1);
}

__global__ void srcsum_fb(const void* __restrict__ ei, const int* __restrict__ deg,
                          unsigned int* __restrict__ Sq, long long E) {
    const bool is32 = detect_is32_wave((const unsigned int*)ei, 2 * E);
    const long long st = (long long)gridDim.x * blockDim.x;
    long long i = blockIdx.x * (long long)blockDim.x + threadIdx.x;
    for (; i < E; i += st)
        atomicAdd(&Sq[ld_e1(ei, is32, i)], quant_w(deg[ld_e1(ei, is32, E + i)] + 1));
}

__global__ void coef_fb(unsigned int* __restrict__ Sq, const int* __restrict__ deg,
                        long long n) {
    const long long v = blockIdx.x * (long long)blockDim.x + threadIdx.x;
    if (v >= n) return;
    unsigned s = Sq[v];
    float dg = (float)(deg[v] + 1);
    float di = rsqrtf(dg);
    ((float*)Sq)[v] = di * ((float)s * QINV) + 1.0f / dg;
}

__global__ void redx_fb(const float* __restrict__ x, const float* __restrict__ coef,
                        float* __restrict__ t, long long n) {
    __shared__ float sm[FD];
    for (int f = threadIdx.x; f < FD; f += blockDim.x) sm[f] = 0.f;
    __syncthreads();
    const long long tot = n * (FD / 4);
    const long long st = (long long)gridDim.x * blockDim.x;
    const int lane = threadIdx.x & 31;
    float4 a = make_float4(0.f, 0.f, 0.f, 0.f);
    for (long long i = blockIdx.x * (long long)blockDim.x + threadIdx.x; i < tot; i += st) {
        float cf = coef[i >> 5];
        float4 xv = reinterpret_cast<const float4*>(x)[i];
        a.x += cf * xv.x; a.y += cf * xv.y; a.z += cf * xv.z; a.w += cf * xv.w;
    }
    atomicAdd(&sm[lane * 4 + 0], a.x);
    atomicAdd(&sm[lane * 4 + 1], a.y);
    atomicAdd(&sm[lane * 4 + 2], a.z);
    atomicAdd(&sm[lane * 4 + 3], a.w);
    __syncthreads();
    for (int f = threadIdx.x; f < FD; f += blockDim.x) atomicAdd(&t[f], sm[f]);
}

__global__ void final_fb(const float* __restrict__ Wm, const float* __restrict__ bias,
                         const float* __restrict__ t, float* __restrict__ out, float nn) {
    __shared__ float ts[FD];
    int f = threadIdx.x;
    if (f < FD) ts[f] = t[f];
    __syncthreads();
    if (f < FD) {
        float a0 = 0.f;
        #pragma unroll 16
        for (int k = 0; k < FD; ++k) a0 += Wm[f * FD + k] * ts[k];
        out[f] = a0 + nn * bias[f];
    }
}

// ==============================================================================
extern "C" void kernel_launch(void* const* d_in, const int* in_sizes, int n_in,
                              void* d_out, int out_size, void* d_ws, size_t ws_size,
                              hipStream_t stream) {
    const float* x    = (const float*)d_in[0];
    const float* W    = (const float*)d_in[1];
    const float* bias = (const float*)d_in[2];
    const void*  ei   = d_in[3];
    float* out = (float*)d_out;
    const long long n = in_sizes[0] / FD;            // 100000
    const long long E = (long long)in_sizes[3] / 2;  // 1600000

    const int NCHD = (int)((n + CHD - 1) / CHD);     // 2
    const int NCHS = (int)((n + CHS - 1) / CHS);     // 7
    const long long SLD = ((E + NSLD - 1) / NSLD + 3) & ~3LL;   // 25000
    const long long capC = (E + 255) & ~255LL;

    char* ws = (char*)d_ws;
    size_t off = 0;
    auto take = [&](size_t bytes) { size_t r = off; off += (bytes + 255) & ~(size_t)255; return r; };
    unsigned int* psD    = (unsigned int*)(ws + take((size_t)NCHD * NSLD * (CHD / 4) * 4));
    unsigned int* psS    = (unsigned int*)(ws + take((size_t)NCHS * NSLS * CHS * 4));
    int*          deg    = (int*)(ws + take((size_t)n * 4));
    unsigned int* qpart  = (unsigned int*)(ws + take((size_t)NCHS * capC * 4));
    unsigned int* counts = (unsigned int*)(ws + take(256));
    float*        P      = (float*)(ws + take((size_t)RXB * FD * 4));
    const size_t need = off;

    const bool main_ok = (ws_size >= need) && ((E & 3) == 0) && (E >= 512) &&
                         (n <= (1LL << 17)) && (NCHS <= 8) &&
                         (n <= (long long)RXB * 1024);

    if (main_ok) {
        hist_deg_kernel<<<NCHD * NSLD, 512, 0, stream>>>(ei, psD, counts, E, SLD, NCHD);
        {
            long long nw = (long long)NCHD * (CHD / 4);
            deg_reduce_kernel<<<(int)((nw + 255) / 256), 256, 0, stream>>>(psD, deg, n, NCHD);
        }
        qwpack_part_kernel<<<QPB, 512, 0, stream>>>(ei, deg, counts, qpart, capC, E, NCHS);
        hist_s_kernel<<<NCHS * NSLS, 512, 0, stream>>>(qpart, counts, psS, capC, NCHS);
        reduce_x_coef_kernel<<<RXB, 256, 0, stream>>>(x, deg, psS, P, n, NCHS);
        colsum_final_kernel<<<FD, 256, 0, stream>>>(P, W, bias, out, (float)n);
    } else {
        int*          degF = (int*)ws;
        unsigned int* Sq   = (unsigned int*)(ws + (size_t)n * 4);
        float*        tF   = (float*)(ws + (size_t)n * 8);
        hipMemsetAsync(ws, 0, (size_t)n * 8 + 512, stream);
        deg_fb<<<1600, 256, 0, stream>>>(ei, degF, E);
        srcsum_fb<<<1600, 256, 0, stream>>>(ei, degF, Sq, E);
        coef_fb<<<(int)((n + 255) / 256), 256, 0, stream>>>(Sq, degF, n);
        redx_fb<<<2048, 256, 0, stream>>>(x, (const float*)Sq, tF, n);
        final_fb<<<1, FD, 0, stream>>>(W, bias, tF, out, (float)n);
    }
}

// Round 13
// 72.760 us; speedup vs baseline: 1.2348x; 1.2348x over previous
//
#include <hip/hip_runtime.h>

#define FD 128
// deg pass: u8 LDS cells, 4 nodes/word, 64 KB -> 65536 nodes/chunk
#define CHD 65536
#define NSLD 64
// S pass: u32 cells, 64 KB LDS
#define CHS 16384
#define NSLS 32
#define RXB 512               // reduce_x blocks
#define QSCALE 16777216.0f    // 2^24 (fallback path)
#define QINV   5.9604644775390625e-8f
#define QS14   16384.0f       // 2^14 (packed qw path)
#define QI14   6.103515625e-5f
#define SRCMASK 0x1FFFFu      // low 17 bits = src id

__device__ __forceinline__ unsigned quant_w(int dp1) {
    return (unsigned)(rsqrtf((float)dp1) * QSCALE + 0.5f);
}
__device__ __forceinline__ unsigned quant_w14(int dp1) {
    return (unsigned)(rsqrtf((float)dp1) * QS14 + 0.5f);   // <= 16384, 15 bits
}

// Wave-level dtype probe (proven R6+): int64 => odd u32 words all zero.
__device__ __forceinline__ bool detect_is32_wave(const unsigned int* w, long long nwords) {
    const int lane = threadIdx.x & 63;
    const long long i0 = 2 * lane + 1, i1 = 2 * (lane + 64) + 1;
    unsigned acc = 0;
    if (i0 < nwords) acc |= w[i0];
    if (i1 < nwords) acc |= w[i1];
    return __ballot(acc != 0u) != 0ull;
}

__device__ __forceinline__ int4 ld_e4(const void* ei, bool is32, long long off, long long i) {
    if (is32) return *reinterpret_cast<const int4*>((const int*)ei + off + i);
    const long long* p = (const long long*)ei + off + i;
    longlong2 a = *reinterpret_cast<const longlong2*>(p);
    longlong2 b = *reinterpret_cast<const longlong2*>(p + 2);
    return make_int4((int)a.x, (int)a.y, (int)b.x, (int)b.y);
}
__device__ __forceinline__ int ld_e1(const void* ei, bool is32, long long idx) {
    return is32 ? ((const int*)ei)[idx] : (int)((const long long*)ei)[idx];
}

// ---- 1: deg histogram over dst, u8 LDS cells (R12-proven) ----
__global__ __launch_bounds__(512) void hist_deg_kernel(
        const void* __restrict__ ei, unsigned int* __restrict__ psD,
        long long E, long long SL, int nch) {
    __shared__ unsigned int hist[CHD / 4];   // 16384 words, 4 u8 cells each
    const int tid = threadIdx.x;
    const bool is32 = detect_is32_wave((const unsigned int*)ei, 2 * E);
    const int b = blockIdx.x, c = b % nch, j = b / nch;
    const int lo = c * CHD;
    for (int i = tid; i < CHD / 4; i += 512) hist[i] = 0u;
    __syncthreads();
    const long long e0 = (long long)j * SL;
    long long e1 = e0 + SL; if (e1 > E) e1 = E; if (e1 < e0) e1 = e0;
    const long long e1v = e0 + ((e1 - e0) & ~3LL);
    for (long long i = e0 + (long long)tid * 4; i < e1v; i += 2048) {
        int4 d = ld_e4(ei, is32, E, i);
        unsigned u0 = (unsigned)(d.x - lo), u1 = (unsigned)(d.y - lo);
        unsigned u2 = (unsigned)(d.z - lo), u3 = (unsigned)(d.w - lo);
        if (u0 < CHD) atomicAdd(&hist[u0 >> 2], 1u << ((u0 & 3) * 8));
        if (u1 < CHD) atomicAdd(&hist[u1 >> 2], 1u << ((u1 & 3) * 8));
        if (u2 < CHD) atomicAdd(&hist[u2 >> 2], 1u << ((u2 & 3) * 8));
        if (u3 < CHD) atomicAdd(&hist[u3 >> 2], 1u << ((u3 & 3) * 8));
    }
    { long long it = e1v + tid;
      if (it < e1) { unsigned u = (unsigned)(ld_e1(ei, is32, E + it) - lo);
                     if (u < CHD) atomicAdd(&hist[u >> 2], 1u << ((u & 3) * 8)); } }
    __syncthreads();
    unsigned int* o = psD + (size_t)b * (CHD / 4);
    for (int w = tid; w < CHD / 4; w += 512) o[w] = hist[w];
}

// ---- 2: reduce u8 deg partials (4 nodes per word, R12-proven) ----
__global__ void deg_reduce_kernel(const unsigned int* __restrict__ psD,
                                  int* __restrict__ deg, long long n, int nch) {
    const long long tw = blockIdx.x * (long long)blockDim.x + threadIdx.x;
    if (tw >= (long long)nch * (CHD / 4)) return;
    const int cc = (int)(tw / (CHD / 4));
    const int w  = (int)(tw % (CHD / 4));
    unsigned s0 = 0, s1 = 0, s2 = 0, s3 = 0;
    for (int j = 0; j < NSLD; ++j) {
        unsigned v = psD[((size_t)j * nch + cc) * (CHD / 4) + w];
        s0 += v & 0xFFu; s1 += (v >> 8) & 0xFFu;
        s2 += (v >> 16) & 0xFFu; s3 += v >> 24;
    }
    const long long v0 = (long long)cc * CHD + 4 * w;
    if (v0 < n)     deg[v0]     = (int)s0;
    if (v0 + 1 < n) deg[v0 + 1] = (int)s1;
    if (v0 + 2 < n) deg[v0 + 2] = (int)s2;
    if (v0 + 3 < n) deg[v0 + 3] = (int)s3;
}

// ---- 3: pack (qw<<17 | src) per edge; qw = round(2^14 * dinv[dst]) (R11-proven) ----
__global__ __launch_bounds__(256) void qwpack_kernel(
        const void* __restrict__ ei, const int* __restrict__ deg,
        unsigned int* __restrict__ qp, long long E) {
    const bool is32 = detect_is32_wave((const unsigned int*)ei, 2 * E);
    const long long stride4 = (long long)gridDim.x * blockDim.x * 4;
    const long long E4 = E & ~3LL;
    for (long long i = (blockIdx.x * (long long)blockDim.x + threadIdx.x) * 4;
         i < E4; i += stride4) {
        int4 s = ld_e4(ei, is32, 0, i);
        int4 d = ld_e4(ei, is32, E, i);
        uint4 q;
        q.x = (quant_w14(deg[d.x] + 1) << 17) | (unsigned)s.x;
        q.y = (quant_w14(deg[d.y] + 1) << 17) | (unsigned)s.y;
        q.z = (quant_w14(deg[d.z] + 1) << 17) | (unsigned)s.z;
        q.w = (quant_w14(deg[d.w] + 1) << 17) | (unsigned)s.w;
        *reinterpret_cast<uint4*>(qp + i) = q;
    }
    const long long st1 = (long long)gridDim.x * blockDim.x;
    for (long long k = E4 + blockIdx.x * (long long)blockDim.x + threadIdx.x;
         k < E; k += st1)
        qp[k] = (quant_w14(deg[ld_e1(ei, is32, E + k)] + 1) << 17) |
                (unsigned)ld_e1(ei, is32, k);
}

// ---- 4: weighted src histogram over single packed stream (R11-proven) ----
__global__ __launch_bounds__(512) void hist_s_kernel(
        const unsigned int* __restrict__ qp, unsigned int* __restrict__ psS,
        long long E, long long SL, int nch) {
    __shared__ unsigned int hist[CHS];
    const int tid = threadIdx.x;
    const int b = blockIdx.x, c = b % nch, j = b / nch;
    const int lo = c * CHS;
    for (int i = tid; i < CHS; i += 512) hist[i] = 0u;
    __syncthreads();
    const long long e0 = (long long)j * SL;
    long long e1 = e0 + SL; if (e1 > E) e1 = E; if (e1 < e0) e1 = e0;
    const long long e1v = e0 + ((e1 - e0) & ~3LL);
    for (long long i = e0 + (long long)tid * 4; i < e1v; i += 2048) {
        uint4 p = *reinterpret_cast<const uint4*>(qp + i);
        unsigned u0 = (p.x & SRCMASK) - lo, u1 = (p.y & SRCMASK) - lo;
        unsigned u2 = (p.z & SRCMASK) - lo, u3 = (p.w & SRCMASK) - lo;
        if (u0 < CHS) atomicAdd(&hist[u0], p.x >> 17);
        if (u1 < CHS) atomicAdd(&hist[u1], p.y >> 17);
        if (u2 < CHS) atomicAdd(&hist[u2], p.z >> 17);
        if (u3 < CHS) atomicAdd(&hist[u3], p.w >> 17);
    }
    { long long it = e1v + tid;
      if (it < e1) { unsigned p = qp[it];
                     unsigned u = (p & SRCMASK) - lo;
                     if (u < CHS) atomicAdd(&hist[u], p >> 17); } }
    __syncthreads();
    unsigned int* o = psS + (size_t)b * CHS;
    for (int w = tid; w < CHS; w += 512) o[w] = hist[w];
}

// ---- 5: merged coef + x reduction (block-contiguous node ranges, R10-proven) ----
__global__ __launch_bounds__(256) void reduce_x_coef_kernel(
        const float* __restrict__ x, const int* __restrict__ deg,
        const unsigned int* __restrict__ psS, float* __restrict__ P,
        long long n, int nch) {
    __shared__ float lcoef[1024];
    __shared__ float4 sm4[256];
    const int tid = threadIdx.x;
    const long long vlo = (long long)blockIdx.x * n / RXB;
    const long long vhi = ((long long)blockIdx.x + 1) * n / RXB;
    const int nv = (int)(vhi - vlo);
    for (int t = tid; t < nv; t += 256) {
        const long long v = vlo + t;
        const int cc = (int)(v / CHS);
        const int u  = (int)(v % CHS);
        unsigned s = 0;
        #pragma unroll 8
        for (int jj = 0; jj < NSLS; ++jj)
            s += psS[((size_t)jj * nch + cc) * CHS + u];
        const float dg = (float)(deg[v] + 1);
        const float di = rsqrtf(dg);
        lcoef[t] = di * ((float)s * QI14) + 1.0f / dg;
    }
    __syncthreads();
    float4 a = make_float4(0.f, 0.f, 0.f, 0.f);
    const long long i0 = vlo * (FD / 4), i1 = vhi * (FD / 4);
    for (long long i = i0 + tid; i < i1; i += 256) {
        const float cf = lcoef[(int)((i >> 5) - vlo)];
        const float4 xv = reinterpret_cast<const float4*>(x)[i];
        a.x += cf * xv.x; a.y += cf * xv.y; a.z += cf * xv.z; a.w += cf * xv.w;
    }
    const int lane = tid & 31, grp = tid >> 5;   // 8 groups of 32
    sm4[grp * 32 + lane] = a;
    __syncthreads();
    for (int s2 = 4; s2 > 0; s2 >>= 1) {
        if (grp < s2) {
            float4 o = sm4[(grp + s2) * 32 + lane];
            float4 m = sm4[grp * 32 + lane];
            m.x += o.x; m.y += o.y; m.z += o.z; m.w += o.w;
            sm4[grp * 32 + lane] = m;
        }
        __syncthreads();
    }
    if (tid < 32) reinterpret_cast<float4*>(P)[blockIdx.x * 32 + tid] = sm4[tid];
}

// ---- 6: fused colsum + W-matvec ----
__global__ __launch_bounds__(256) void colsum_final_kernel(
        const float* __restrict__ P, const float* __restrict__ Wm,
        const float* __restrict__ bias, float* __restrict__ out, float nn) {
    __shared__ float wrow[FD];
    __shared__ float red[256];
    const int f = blockIdx.x, tid = threadIdx.x;
    if (tid < FD) wrow[tid] = Wm[f * FD + tid];
    __syncthreads();
    float part = 0.f;
    for (int j = tid; j < RXB; j += 256) {
        const float4* Pj = reinterpret_cast<const float4*>(P + (size_t)j * FD);
        #pragma unroll
        for (int k = 0; k < FD / 4; ++k) {
            float4 p = Pj[k];
            part += wrow[4 * k] * p.x + wrow[4 * k + 1] * p.y +
                    wrow[4 * k + 2] * p.z + wrow[4 * k + 3] * p.w;
        }
    }
    red[tid] = part;
    __syncthreads();
    for (int s2 = 128; s2 > 0; s2 >>= 1) {
        if (tid < s2) red[tid] += red[tid + s2];
        __syncthreads();
    }
    if (tid == 0) out[f] = red[0] + nn * bias[f];
}

// ================= fallback (R2-proven global-atomic path) =================
__global__ void deg_fb(const void* __restrict__ ei, int* __restrict__ deg, long long E) {
    const bool is32 = detect_is32_wave((const unsigned int*)ei, 2 * E);
    const long long st = (long long)gridDim.x * blockDim.x;
    long long i = blockIdx.x * (long long)blockDim.x + threadIdx.x;
    for (; i < E; i += st) atomicAdd(&deg[ld_e1(ei, is32, E + i)], 1);
}

__global__ void srcsum_fb(const void* __restrict__ ei, const int* __restrict__ deg,
                          unsigned int* __restrict__ Sq, long long E) {
    const bool is32 = detect_is32_wave((const unsigned int*)ei, 2 * E);
    const long long st = (long long)gridDim.x * blockDim.x;
    long long i = blockIdx.x * (long long)blockDim.x + threadIdx.x;
    for (; i < E; i += st)
        atomicAdd(&Sq[ld_e1(ei, is32, i)], quant_w(deg[ld_e1(ei, is32, E + i)] + 1));
}

__global__ void coef_fb(unsigned int* __restrict__ Sq, const int* __restrict__ deg,
                        long long n) {
    const long long v = blockIdx.x * (long long)blockDim.x + threadIdx.x;
    if (v >= n) return;
    unsigned s = Sq[v];
    float dg = (float)(deg[v] + 1);
    float di = rsqrtf(dg);
    ((float*)Sq)[v] = di * ((float)s * QINV) + 1.0f / dg;
}

__global__ void redx_fb(const float* __restrict__ x, const float* __restrict__ coef,
                        float* __restrict__ t, long long n) {
    __shared__ float sm[FD];
    for (int f = threadIdx.x; f < FD; f += blockDim.x) sm[f] = 0.f;
    __syncthreads();
    const long long tot = n * (FD / 4);
    const long long st = (long long)gridDim.x * blockDim.x;
    const int lane = threadIdx.x & 31;
    float4 a = make_float4(0.f, 0.f, 0.f, 0.f);
    for (long long i = blockIdx.x * (long long)blockDim.x + threadIdx.x; i < tot; i += st) {
        float cf = coef[i >> 5];
        float4 xv = reinterpret_cast<const float4*>(x)[i];
        a.x += cf * xv.x; a.y += cf * xv.y; a.z += cf * xv.z; a.w += cf * xv.w;
    }
    atomicAdd(&sm[lane * 4 + 0], a.x);
    atomicAdd(&sm[lane * 4 + 1], a.y);
    atomicAdd(&sm[lane * 4 + 2], a.z);
    atomicAdd(&sm[lane * 4 + 3], a.w);
    __syncthreads();
    for (int f = threadIdx.x; f < FD; f += blockDim.x) atomicAdd(&t[f], sm[f]);
}

__global__ void final_fb(const float* __restrict__ Wm, const float* __restrict__ bias,
                         const float* __restrict__ t, float* __restrict__ out, float nn) {
    __shared__ float ts[FD];
    int f = threadIdx.x;
    if (f < FD) ts[f] = t[f];
    __syncthreads();
    if (f < FD) {
        float a0 = 0.f;
        #pragma unroll 16
        for (int k = 0; k < FD; ++k) a0 += Wm[f * FD + k] * ts[k];
        out[f] = a0 + nn * bias[f];
    }
}

// ==============================================================================
extern "C" void kernel_launch(void* const* d_in, const int* in_sizes, int n_in,
                              void* d_out, int out_size, void* d_ws, size_t ws_size,
                              hipStream_t stream) {
    const float* x    = (const float*)d_in[0];
    const float* W    = (const float*)d_in[1];
    const float* bias = (const float*)d_in[2];
    const void*  ei   = d_in[3];
    float* out = (float*)d_out;
    const long long n = in_sizes[0] / FD;            // 100000
    const long long E = (long long)in_sizes[3] / 2;  // 1600000

    const int NCHD = (int)((n + CHD - 1) / CHD);     // 2
    const int NCHS = (int)((n + CHS - 1) / CHS);     // 7
    const long long SLD = ((E + NSLD - 1) / NSLD + 3) & ~3LL;   // 25000
    const long long SLS = ((E + NSLS - 1) / NSLS + 3) & ~3LL;   // 50000

    char* ws = (char*)d_ws;
    size_t off = 0;
    auto take = [&](size_t bytes) { size_t r = off; off += (bytes + 255) & ~(size_t)255; return r; };
    unsigned int* psD = (unsigned int*)(ws + take((size_t)NCHD * NSLD * (CHD / 4) * 4));
    unsigned int* psS = (unsigned int*)(ws + take((size_t)NCHS * NSLS * CHS * 4));
    int*          deg = (int*)(ws + take((size_t)n * 4));
    unsigned int* qp  = (unsigned int*)(ws + take((size_t)E * 4));
    float*        P   = (float*)(ws + take((size_t)RXB * FD * 4));
    const size_t need = off;

    const bool main_ok = (ws_size >= need) && ((E & 3) == 0) && (E >= 512) &&
                         (SLD < 65536) && (n <= (1LL << 17)) &&
                         (n <= (long long)RXB * 1024);

    if (main_ok) {
        hist_deg_kernel<<<NCHD * NSLD, 512, 0, stream>>>(ei, psD, E, SLD, NCHD);
        {
            long long nw = (long long)NCHD * (CHD / 4);
            deg_reduce_kernel<<<(int)((nw + 255) / 256), 256, 0, stream>>>(psD, deg, n, NCHD);
        }
        qwpack_kernel<<<1024, 256, 0, stream>>>(ei, deg, qp, E);
        hist_s_kernel<<<NCHS * NSLS, 512, 0, stream>>>(qp, psS, E, SLS, NCHS);
        reduce_x_coef_kernel<<<RXB, 256, 0, stream>>>(x, deg, psS, P, n, NCHS);
        colsum_final_kernel<<<FD, 256, 0, stream>>>(P, W, bias, out, (float)n);
    } else {
        int*          degF = (int*)ws;
        unsigned int* Sq   = (unsigned int*)(ws + (size_t)n * 4);
        float*        tF   = (float*)(ws + (size_t)n * 8);
        hipMemsetAsync(ws, 0, (size_t)n * 8 + 512, stream);
        deg_fb<<<1600, 256, 0, stream>>>(ei, degF, E);
        srcsum_fb<<<1600, 256, 0, stream>>>(ei, degF, Sq, E);
        coef_fb<<<(int)((n + 255) / 256), 256, 0, stream>>>(Sq, degF, n);
        redx_fb<<<2048, 256, 0, stream>>>(x, (const float*)Sq, tF, n);
        final_fb<<<1, FD, 0, stream>>>(W, bias, tF, out, (float)n);
    }
}